// Round 2
// baseline (19.396 us; speedup 1.0000x reference)
//
#include <hip/hip_runtime.h>

#define P 1024
#define C 8
#define D 8
#define K 8
#define WPB 4            // waves per block; one output row b per wave
#define AITER (P / 64)   // 16 a-iterations per lane

// out[n,d,b] = sum_{k,c} W[d,c,k] * T[k,c]
// T[k,c]     = sum_a exp(-8*(r[b,a]-ck)^2) * mask[b,a] * input[c,a]
__global__ __launch_bounds__(256, 2) void se3_conv_kernel(
    const float* __restrict__ input,   // [n, C, P]
    const float* __restrict__ diff,    // [n, P, P, 3]
    const float* __restrict__ mask,    // [n, P, P]
    const float* __restrict__ W,       // [D, C, K]
    float* __restrict__ out)           // [n, D, P]
{
    __shared__ float inp_lds[C * P];   // 32 KB, input[n] staged once
    __shared__ float Tl[WPB][64];      // per-wave T[k*8+c]

    const int n    = blockIdx.y;
    const int tid  = threadIdx.x;
    const int lane = tid & 63;
    const int wave = tid >> 6;
    const int b    = blockIdx.x * WPB + wave;

    // ---- stage input[n] (L2-hot, 32 KB) into LDS with float4 loads ----
    {
        const float4* src = (const float4*)(input + (size_t)n * C * P);
        float4* dst = (float4*)inp_lds;
        #pragma unroll
        for (int i = 0; i < (C * P / 4) / 256; ++i)
            dst[tid + i * 256] = src[tid + i * 256];
    }
    __syncthreads();

    const float* diff_row = diff + (((size_t)n * P + b) * P) * 3;
    const float* mask_row = mask + ((size_t)n * P + b) * P;

    float acc[K * C];
    #pragma unroll
    for (int i = 0; i < K * C; ++i) acc[i] = 0.0f;

    // basis_k(r)*m = exp2( L2E*(-8 r^2) + fma(L2E*16*ck, r, -L2E*8*ck^2) ) * m
    const float L2E = 1.44269504f;

    #pragma unroll 4
    for (int j = 0; j < AITER; ++j) {
        const int a = lane + j * 64;
        const float x = diff_row[a * 3 + 0];
        const float y = diff_row[a * 3 + 1];
        const float z = diff_row[a * 3 + 2];
        const float m = mask_row[a];

        const float r2 = fmaf(x, x, fmaf(y, y, z * z));
        const float r  = sqrtf(r2);
        const float u  = -8.0f * L2E * r2;

        float basis[K];
        #pragma unroll
        for (int k = 0; k < K; ++k) {
            const float ck = (2.0f / 7.0f) * (float)k;
            const float c1 = 16.0f * L2E * ck;
            const float c0 = -8.0f * L2E * ck * ck;
            basis[k] = exp2f(fmaf(c1, r, c0) + u) * m;
        }

        float inp[C];
        #pragma unroll
        for (int c = 0; c < C; ++c) inp[c] = inp_lds[c * P + a];

        #pragma unroll
        for (int k = 0; k < K; ++k)
            #pragma unroll
            for (int c = 0; c < C; ++c)
                acc[k * C + c] = fmaf(basis[k], inp[c], acc[k * C + c]);
    }

    // ---- wave-level reduce-scatter (recursive halving) ----
    // After 6 steps lane l holds the wave-total of acc[bitrev6(l)].
    #pragma unroll
    for (int s = 0; s < 6; ++s) {
        const int half = 32 >> s;
        const int bit  = (lane >> s) & 1;
        #pragma unroll
        for (int i = 0; i < half; ++i) {
            const float send = bit ? acc[i] : acc[i + half];
            const float recv = __shfl_xor(send, 1 << s, 64);
            const float keep = bit ? acc[i + half] : acc[i];
            acc[i] = keep + recv;
        }
    }

    const int j64 = (int)(__brev((unsigned)lane) >> 26);  // bitrev6(lane)
    Tl[wave][j64] = acc[0];
    __syncthreads();   // uniform; orders the per-wave LDS write vs read

    // ---- parallel W contraction: lane = d*8 + k8 ----
    const int d  = lane >> 3;
    const int k8 = lane & 7;
    float part = 0.0f;
    #pragma unroll
    for (int m = 0; m < 8; ++m)
        part += W[d * 64 + m * 8 + k8] * Tl[wave][k8 * 8 + m];
    part += __shfl_xor(part, 1, 64);
    part += __shfl_xor(part, 2, 64);
    part += __shfl_xor(part, 4, 64);
    if (k8 == 0)
        out[((size_t)n * D + d) * P + b] = part;
}

extern "C" void kernel_launch(void* const* d_in, const int* in_sizes, int n_in,
                              void* d_out, int out_size, void* d_ws, size_t ws_size,
                              hipStream_t stream) {
    const float* input = (const float*)d_in[0];   // [2, 8, 1024]
    const float* diff  = (const float*)d_in[1];   // [2, 1024, 1024, 3]
    const float* mask  = (const float*)d_in[2];   // [2, 1024, 1024]
    const float* W     = (const float*)d_in[3];   // [8, 8, 8]
    float* out = (float*)d_out;                   // [2, 8, 1024]

    dim3 grid(P / WPB, 2);
    se3_conv_kernel<<<grid, 256, 0, stream>>>(input, diff, mask, W, out);
}

// Round 3
// 15.765 us; speedup vs baseline: 1.2303x; 1.2303x over previous
//
#include <hip/hip_runtime.h>

#define P 1024
#define C 8
#define D 8
#define K 8
#define WPB 4            // waves per block; one output row b per wave
#define NITER (P / 64)   // 16 a-iterations per lane

// out[n,d,b] = sum_{k,c} W[d,c,k] * T[k,c]
// T[k,c]     = sum_a exp(-8*(r[b,a]-ck)^2) * mask[b,a] * input[c,a]
__global__ __launch_bounds__(256, 2) void se3_conv_kernel(
    const float* __restrict__ input,   // [n, C, P]
    const float* __restrict__ diff,    // [n, P, P, 3]
    const float* __restrict__ mask,    // [n, P, P]
    const float* __restrict__ W,       // [D, C, K]
    float* __restrict__ out)           // [n, D, P]
{
    __shared__ float inp_lds[C * P];   // 32 KB, input[n] staged once per block
    __shared__ float Tl[WPB][64];

    const int n    = blockIdx.y;
    const int tid  = threadIdx.x;
    const int lane = tid & 63;
    const int wave = tid >> 6;
    const int b    = blockIdx.x * WPB + wave;

    // ---- stage input[n] (32 KB, L2-hot) into LDS with float4 loads ----
    {
        const float4* src = (const float4*)(input + (size_t)n * C * P);
        float4* dst = (float4*)inp_lds;
        #pragma unroll
        for (int i = 0; i < (C * P / 4) / 256; ++i)
            dst[tid + i * 256] = src[tid + i * 256];
    }

    // ---- issue ALL diff/mask loads up front: 16 KB/wave in flight ----
    const float* diff_row = diff + (((size_t)n * P + b) * P) * 3;
    const float* mask_row = mask + ((size_t)n * P + b) * P;

    float xv[NITER], yv[NITER], zv[NITER], mv[NITER];
    #pragma unroll
    for (int j = 0; j < NITER; ++j) {
        const float* p = diff_row + (size_t)(lane + j * 64) * 3;
        xv[j] = p[0];
        yv[j] = p[1];
        zv[j] = p[2];
        mv[j] = mask_row[lane + j * 64];
    }

    __syncthreads();   // drains staging + prefetch; the ONE exposed latency

    float acc[K * C];
    #pragma unroll
    for (int i = 0; i < K * C; ++i) acc[i] = 0.0f;

    const float L2E = 1.44269504f;
    // basis_k(r)*m = exp2( -8*L2E*r^2 + fma(16*L2E*ck, r, -8*L2E*ck^2) ) * m

    #pragma unroll
    for (int j = 0; j < NITER; ++j) {
        const int a = lane + j * 64;
        const float x = xv[j], y = yv[j], z = zv[j], m = mv[j];

        const float r2 = fmaf(x, x, fmaf(y, y, z * z));
        const float r  = sqrtf(r2);
        const float u  = -8.0f * L2E * r2;

        float basis[K];
        #pragma unroll
        for (int k = 0; k < K; ++k) {
            const float ck = (2.0f / 7.0f) * (float)k;
            const float c1 = 16.0f * L2E * ck;
            const float c0 = -8.0f * L2E * ck * ck;
            basis[k] = __builtin_amdgcn_exp2f(fmaf(c1, r, c0) + u) * m;
        }

        float inp[C];
        #pragma unroll
        for (int c = 0; c < C; ++c) inp[c] = inp_lds[c * P + a];

        #pragma unroll
        for (int k = 0; k < K; ++k)
            #pragma unroll
            for (int c = 0; c < C; ++c)
                acc[k * C + c] = fmaf(basis[k], inp[c], acc[k * C + c]);
    }

    // ---- wave-level reduce-scatter (recursive halving) ----
    // After 6 steps lane l holds the wave-total of acc[bitrev6(l)].
    #pragma unroll
    for (int s = 0; s < 6; ++s) {
        const int half = 32 >> s;
        const int bit  = (lane >> s) & 1;
        #pragma unroll
        for (int i = 0; i < half; ++i) {
            const float send = bit ? acc[i] : acc[i + half];
            const float recv = __shfl_xor(send, 1 << s, 64);
            const float keep = bit ? acc[i + half] : acc[i];
            acc[i] = keep + recv;
        }
    }

    const int j64 = (int)(__brev((unsigned)lane) >> 26);  // bitrev6(lane)
    Tl[wave][j64] = acc[0];
    __syncthreads();   // uniform; orders per-wave LDS write vs read

    // ---- parallel W contraction: lane = d*8 + k8 ----
    const int d  = lane >> 3;
    const int k8 = lane & 7;
    float part = 0.0f;
    #pragma unroll
    for (int q = 0; q < 8; ++q)
        part += W[d * 64 + q * 8 + k8] * Tl[wave][k8 * 8 + q];
    part += __shfl_xor(part, 1, 64);
    part += __shfl_xor(part, 2, 64);
    part += __shfl_xor(part, 4, 64);
    if (k8 == 0)
        out[((size_t)n * D + d) * P + b] = part;
}

extern "C" void kernel_launch(void* const* d_in, const int* in_sizes, int n_in,
                              void* d_out, int out_size, void* d_ws, size_t ws_size,
                              hipStream_t stream) {
    const float* input = (const float*)d_in[0];   // [2, 8, 1024]
    const float* diff  = (const float*)d_in[1];   // [2, 1024, 1024, 3]
    const float* mask  = (const float*)d_in[2];   // [2, 1024, 1024]
    const float* W     = (const float*)d_in[3];   // [8, 8, 8]
    float* out = (float*)d_out;                   // [2, 8, 1024]

    dim3 grid(P / WPB, 2);
    se3_conv_kernel<<<grid, 256, 0, stream>>>(input, diff, mask, W, out);
}

// Round 4
// 14.865 us; speedup vs baseline: 1.3048x; 1.0605x over previous
//
#include <hip/hip_runtime.h>

#define P 1024
#define C 8
#define D 8
#define K 8
#define WPB 4              // waves per block; one output row b per wave
#define NITER (P / 64)     // 16 a-iterations per lane
#define CHUNK 4
#define NCHUNK (NITER / CHUNK)

// out[n,d,b] = sum_{k,c} W[d,c,k] * T[k,c]
// T[k,c]     = sum_a exp(-8*(r[b,a]-ck)^2) * mask[b,a] * input[c,a]
__global__ __launch_bounds__(256, 2) void se3_conv_kernel(
    const float* __restrict__ input,   // [n, C, P]
    const float* __restrict__ diff,    // [n, P, P, 3]
    const float* __restrict__ mask,    // [n, P, P]
    const float* __restrict__ W,       // [D, C, K]
    float* __restrict__ out)           // [n, D, P]
{
    __shared__ float inp_lds[C * P];   // 32 KB, input[n] staged once per block
    __shared__ float Tl[WPB][64];

    const int n    = blockIdx.y;
    const int tid  = threadIdx.x;
    const int lane = tid & 63;
    const int wave = tid >> 6;
    const int b    = blockIdx.x * WPB + wave;

    const float* diff_row = diff + (((size_t)n * P + b) * P) * 3;
    const float* mask_row = mask + ((size_t)n * P + b) * P;

    float xv[NITER], yv[NITER], zv[NITER], mv[NITER];

    // ---- issue chunk 0 prefetch (head start before the barrier) ----
    #pragma unroll
    for (int j = 0; j < CHUNK; ++j) {
        const float* p = diff_row + (size_t)(lane + j * 64) * 3;
        xv[j] = p[0];
        yv[j] = p[1];
        zv[j] = p[2];
        mv[j] = mask_row[lane + j * 64];
    }

    // ---- stage input[n] (32 KB, L2-hot) into LDS with float4 loads ----
    {
        const float4* src = (const float4*)(input + (size_t)n * C * P);
        float4* dst = (float4*)inp_lds;
        #pragma unroll
        for (int i = 0; i < (C * P / 4) / 256; ++i)
            dst[tid + i * 256] = src[tid + i * 256];
    }

    float acc[K * C];
    #pragma unroll
    for (int i = 0; i < K * C; ++i) acc[i] = 0.0f;

    __syncthreads();   // the ONE exposed latency (staging + chunk 0)

    const float L2E = 1.44269504f;
    // basis_k(r)*m = exp2( -8*L2E*r^2 + 16*L2E*ck*r - 8*L2E*ck^2 ) * m

    #pragma unroll
    for (int ch = 0; ch < NCHUNK; ++ch) {
        // issue next chunk's loads; NO barrier -> counted vmcnt waits,
        // these stream while we compute the current chunk
        if (ch + 1 < NCHUNK) {
            #pragma unroll
            for (int jj = 0; jj < CHUNK; ++jj) {
                const int j = (ch + 1) * CHUNK + jj;
                const float* p = diff_row + (size_t)(lane + j * 64) * 3;
                xv[j] = p[0];
                yv[j] = p[1];
                zv[j] = p[2];
                mv[j] = mask_row[lane + j * 64];
            }
        }

        #pragma unroll
        for (int jj = 0; jj < CHUNK; ++jj) {
            const int j = ch * CHUNK + jj;
            const int a = lane + j * 64;
            const float x = xv[j], y = yv[j], z = zv[j], m = mv[j];

            const float r2 = fmaf(x, x, fmaf(y, y, z * z));
            const float r  = __builtin_amdgcn_sqrtf(r2);
            const float u  = -8.0f * L2E * r2;

            float basis[K];
            #pragma unroll
            for (int k = 0; k < K; ++k) {
                const float ck = (2.0f / 7.0f) * (float)k;
                const float c1 = 16.0f * L2E * ck;
                const float c0 = -8.0f * L2E * ck * ck;
                basis[k] = __builtin_amdgcn_exp2f(fmaf(c1, r, u + c0)) * m;
            }

            float inp[C];
            #pragma unroll
            for (int c = 0; c < C; ++c) inp[c] = inp_lds[c * P + a];

            #pragma unroll
            for (int k = 0; k < K; ++k)
                #pragma unroll
                for (int c = 0; c < C; ++c)
                    acc[k * C + c] = fmaf(basis[k], inp[c], acc[k * C + c]);
        }
    }

    // ---- wave-level reduce-scatter (recursive halving) ----
    // After 6 steps lane l holds the wave-total of acc[bitrev6(l)].
    #pragma unroll
    for (int s = 0; s < 6; ++s) {
        const int half = 32 >> s;
        const int bit  = (lane >> s) & 1;
        #pragma unroll
        for (int i = 0; i < half; ++i) {
            const float send = bit ? acc[i] : acc[i + half];
            const float recv = __shfl_xor(send, 1 << s, 64);
            const float keep = bit ? acc[i + half] : acc[i];
            acc[i] = keep + recv;
        }
    }

    const int j64 = (int)(__brev((unsigned)lane) >> 26);  // bitrev6(lane)
    Tl[wave][j64] = acc[0];
    __syncthreads();   // uniform; orders per-wave LDS write vs read

    // ---- parallel W contraction: lane = d*8 + k8 ----
    const int d  = lane >> 3;
    const int k8 = lane & 7;
    float part = 0.0f;
    #pragma unroll
    for (int q = 0; q < 8; ++q)
        part += W[d * 64 + q * 8 + k8] * Tl[wave][k8 * 8 + q];
    part += __shfl_xor(part, 1, 64);
    part += __shfl_xor(part, 2, 64);
    part += __shfl_xor(part, 4, 64);
    if (k8 == 0)
        out[((size_t)n * D + d) * P + b] = part;
}

extern "C" void kernel_launch(void* const* d_in, const int* in_sizes, int n_in,
                              void* d_out, int out_size, void* d_ws, size_t ws_size,
                              hipStream_t stream) {
    const float* input = (const float*)d_in[0];   // [2, 8, 1024]
    const float* diff  = (const float*)d_in[1];   // [2, 1024, 1024, 3]
    const float* mask  = (const float*)d_in[2];   // [2, 1024, 1024]
    const float* W     = (const float*)d_in[3];   // [8, 8, 8]
    float* out = (float*)d_out;                   // [2, 8, 1024]

    dim3 grid(P / WPB, 2);
    se3_conv_kernel<<<grid, 256, 0, stream>>>(input, diff, mask, W, out);
}